// Round 9
// baseline (4041.758 us; speedup 1.0000x reference)
//
#include <hip/hip_runtime.h>
#include <hip/hip_bf16.h>

// Qwen2 attention layer, MI355X/gfx950.
// B=2 S=2048 HID=3584 NH=28 NKV=4 D=128, causal, GQA groups=7.
// Round 9 (= round 8 + permlane32_swap corrected):
//  v_permlane32_swap_b32 swaps HIGH(VDST) <-> LOW(VSRC):
//    ret = swap(A,B): ret[0] = [A_lo | B_lo(->hi)], ret[1] = [A_hi(->lo) | B_hi]
//  so B-frag words come from swap(w[k], w[k+2]) with word_lo = ret[0],
//  word_hi = ret[1] (HK T12 pattern).
//
// Workspace layout (bytes), total ~99.5 MB:
//   Xb    @ 0          29,360,128  (B*S x HID bf16)      -> reused as AOb after QKV GEMM
//   Wcat  @ 29,360,128 33,030,144  (4608 x 3584 bf16)    -> reused as Wo-bf16 after QKV GEMM
//   bcat  @ 62,390,272 18,432      (4608 f32)
//   QKVb  @ 62,408,704 37,748,736  (B*S x 4608 bf16)
//   Vt    @ 100,157,440 4,194,304  (B*NKV*128 x S bf16)

#define HID   3584
#define NHQ   28
#define NKVH  4
#define HD    128
#define SEQ   2048
#define NQKV  4608
#define GRP   7

typedef __attribute__((ext_vector_type(8))) short bf16x8;
typedef __attribute__((ext_vector_type(4))) float f32x4;
typedef __attribute__((ext_vector_type(16))) float f32x16;
typedef __attribute__((ext_vector_type(4))) int int4v;

#define BARRIER() asm volatile("s_barrier" ::: "memory")

__device__ __forceinline__ void gload_lds16(const void* g, void* l) {
  __builtin_amdgcn_global_load_lds(
      (const __attribute__((address_space(1))) void*)g,
      (__attribute__((address_space(3))) void*)l, 16, 0, 0);
}

__device__ __forceinline__ unsigned short f2bf(float f) {
  __hip_bfloat16 h = __float2bfloat16(f);
  return *reinterpret_cast<unsigned short*>(&h);
}

__device__ __forceinline__ float bf2f(unsigned short u) {
  __hip_bfloat16 h = *reinterpret_cast<__hip_bfloat16*>(&u);
  return __bfloat162float(h);
}

// ---------------- f32 -> bf16 conversion (vectorized, 4 elems/thread) ------
__global__ __launch_bounds__(256)
void cvt_f32_bf16(const float* __restrict__ src, __hip_bfloat16* __restrict__ dst, int n4) {
  int i = blockIdx.x * 256 + threadIdx.x;
  if (i >= n4) return;
  float4 v = ((const float4*)src)[i];
  ushort4 o;
  o.x = f2bf(v.x); o.y = f2bf(v.y); o.z = f2bf(v.z); o.w = f2bf(v.w);
  ((ushort4*)dst)[i] = o;
}

__global__ __launch_bounds__(256)
void concat_bias(const float* __restrict__ bq, const float* __restrict__ bk,
                 const float* __restrict__ bv, float* __restrict__ out) {
  int i = blockIdx.x * 256 + threadIdx.x;
  if (i < HID) out[i] = bq[i];
  else if (i < HID + 512) out[i] = bk[i - HID];
  else if (i < NQKV) out[i] = bv[i - HID - 512];
}

// ---------------- GEMM: C[M][N] = A[M][K] * B[N][K]^T (+bias) --------------
// 256x256 tile, BK=64, 8 waves, dbuf LDS, 8-phase counted-vmcnt schedule.
// 1D grid with bijective XCD swizzle (m204).
template<bool HAS_BIAS, bool OUT_BF16>
__global__ __launch_bounds__(512, 2)
void gemm256(const __hip_bfloat16* __restrict__ A, const __hip_bfloat16* __restrict__ Bm,
             const float* __restrict__ bias, void* __restrict__ Cv,
             int M, int N, int K, int nmt) {
  __shared__ __align__(16) char lds[131072];
  const int tid = threadIdx.x;
  const int w = tid >> 6, l = tid & 63;
  const int g = l >> 4, r = l & 15;
  const int wr = w >> 2, wc = w & 3;

  // bijective XCD swizzle (nwg % 8 == 0 for both our grids)
  const int nwg = gridDim.x;
  const int qq = nwg >> 3, r8 = nwg & 7;
  const int xcd = blockIdx.x & 7, idx = blockIdx.x >> 3;
  const int wgid = (xcd < r8 ? xcd * (qq + 1) : r8 * (qq + 1) + (xcd - r8) * qq) + idx;
  const int bm = (wgid % nmt) * 256, bn = (wgid / nmt) * 256;

  const int NKT = K >> 6;
  const size_t Kb2 = (size_t)K * 2;
  const int swz = (r & 7) << 4;

  auto issueHalf = [&](int kt, int h) {
    const char* src = (h < 2) ? (const char*)A : (const char*)Bm;
    const int rbase = (h < 2) ? bm : bn;
    char* reg = lds + (kt & 1) * 65536 + ((h < 2) ? 0 : 32768);
#pragma unroll
    for (int i = 0; i < 2; ++i) {
      const int lrow = (h & 1) * 128 + w * 16 + i * 8;   // wave-uniform dest row
      const int row = lrow + (l >> 3);                    // per-lane source row
      const int cb = (l & 7) * 16;
      gload_lds16(src + (size_t)(rbase + row) * Kb2 + (size_t)kt * 128 + (cb ^ ((row & 7) << 4)),
                  reg + lrow * 128);
    }
  };

  auto ldA = [&](int d, int mf, int kk) -> bf16x8 {
    const int row = wr * 128 + mf * 16 + r;
    return *(const bf16x8*)(lds + d * 65536 + row * 128 + ((kk * 64 + g * 16) ^ swz));
  };
  auto ldB = [&](int d, int nf, int kk) -> bf16x8 {
    const int row = wc * 64 + nf * 16 + r;
    return *(const bf16x8*)(lds + d * 65536 + 32768 + row * 128 + ((kk * 64 + g * 16) ^ swz));
  };

  f32x4 acc[8][4];
#pragma unroll
  for (int m = 0; m < 8; m++)
#pragma unroll
    for (int n = 0; n < 4; n++) acc[m][n] = (f32x4){0.f, 0.f, 0.f, 0.f};

#pragma unroll
  for (int h = 0; h < 4; ++h) issueHalf(0, h);
#pragma unroll
  for (int h = 0; h < 4; ++h) issueHalf(1, h);
  asm volatile("s_waitcnt vmcnt(8)" ::: "memory");
  BARRIER();

  bf16x8 af[4][2], bfr[4][2];

#pragma unroll 1
  for (int kt = 0; kt < NKT; ++kt) {
    const int d = kt & 1;

    if (kt >= 1 && kt + 1 < NKT) { issueHalf(kt + 1, 1); issueHalf(kt + 1, 3); }
#pragma unroll
    for (int mf = 0; mf < 4; mf++)
#pragma unroll
      for (int kk = 0; kk < 2; kk++) af[mf][kk] = ldA(d, mf, kk);
#pragma unroll
    for (int nf = 0; nf < 2; nf++)
#pragma unroll
      for (int kk = 0; kk < 2; kk++) bfr[nf][kk] = ldB(d, nf, kk);
    BARRIER();
    __builtin_amdgcn_s_setprio(1);
#pragma unroll
    for (int mf = 0; mf < 4; mf++)
#pragma unroll
      for (int nf = 0; nf < 2; nf++)
#pragma unroll
        for (int kk = 0; kk < 2; kk++)
          acc[mf][nf] = __builtin_amdgcn_mfma_f32_16x16x32_bf16(af[mf][kk], bfr[nf][kk], acc[mf][nf], 0, 0, 0);
    __builtin_amdgcn_s_setprio(0);
    BARRIER();

#pragma unroll
    for (int nf = 2; nf < 4; nf++)
#pragma unroll
      for (int kk = 0; kk < 2; kk++) bfr[nf][kk] = ldB(d, nf, kk);
    BARRIER();
    __builtin_amdgcn_s_setprio(1);
#pragma unroll
    for (int mf = 0; mf < 4; mf++)
#pragma unroll
      for (int nf = 2; nf < 4; nf++)
#pragma unroll
        for (int kk = 0; kk < 2; kk++)
          acc[mf][nf] = __builtin_amdgcn_mfma_f32_16x16x32_bf16(af[mf][kk], bfr[nf][kk], acc[mf][nf], 0, 0, 0);
    __builtin_amdgcn_s_setprio(0);
    BARRIER();

    if (kt + 2 < NKT) issueHalf(kt + 2, 2);
#pragma unroll
    for (int mf = 0; mf < 4; mf++)
#pragma unroll
      for (int kk = 0; kk < 2; kk++) af[mf][kk] = ldA(d, mf + 4, kk);
    BARRIER();
    __builtin_amdgcn_s_setprio(1);
#pragma unroll
    for (int mf = 0; mf < 4; mf++)
#pragma unroll
      for (int nf = 0; nf < 2; nf++)
#pragma unroll
        for (int kk = 0; kk < 2; kk++)
          acc[mf + 4][nf] = __builtin_amdgcn_mfma_f32_16x16x32_bf16(af[mf][kk], bfr[nf][kk], acc[mf + 4][nf], 0, 0, 0);
    __builtin_amdgcn_s_setprio(0);
    BARRIER();

    if (kt + 2 < NKT) {
      issueHalf(kt + 2, 0);
      asm volatile("s_waitcnt vmcnt(4)" ::: "memory");
    } else if (kt + 1 < NKT) {
      asm volatile("s_waitcnt vmcnt(0)" ::: "memory");
    }
    BARRIER();
    __builtin_amdgcn_s_setprio(1);
#pragma unroll
    for (int mf = 0; mf < 4; mf++)
#pragma unroll
      for (int nf = 2; nf < 4; nf++)
#pragma unroll
        for (int kk = 0; kk < 2; kk++)
          acc[mf + 4][nf] = __builtin_amdgcn_mfma_f32_16x16x32_bf16(af[mf][kk], bfr[nf][kk], acc[mf + 4][nf], 0, 0, 0);
    __builtin_amdgcn_s_setprio(0);
    BARRIER();
  }

#pragma unroll
  for (int nf = 0; nf < 4; nf++) {
    const int gcol = bn + wc * 64 + nf * 16 + r;
    const float bv = HAS_BIAS ? bias[gcol] : 0.f;
#pragma unroll
    for (int mf = 0; mf < 8; mf++) {
#pragma unroll
      for (int j = 0; j < 4; j++) {
        const int grow = bm + wr * 128 + mf * 16 + 4 * g + j;
        float v = acc[mf][nf][j] + bv;
        if constexpr (OUT_BF16)
          ((__hip_bfloat16*)Cv)[(size_t)grow * N + gcol] = __float2bfloat16(v);
        else
          ((float*)Cv)[(size_t)grow * N + gcol] = v;
      }
    }
  }
}

// ---------------- RoPE on Q and K head slots (in-place, bf16, x4 vec) ------
__global__ __launch_bounds__(256)
void rope_qk(__hip_bfloat16* __restrict__ QKV, const float* __restrict__ cosb,
             const float* __restrict__ sinb) {
  int i = blockIdx.x * 256 + threadIdx.x;   // 2,097,152 threads
  int d = (i & 15) * 4;
  int hh = (i >> 4) & 31;
  int row = i >> 9;
  int cb = (hh < NHQ) ? hh * HD : HID + (hh - NHQ) * HD;
  unsigned short* base = (unsigned short*)QKV + (size_t)row * NQKV + cb;
  float4 c = *(const float4*)&cosb[row * HD + d];
  float4 sn = *(const float4*)&sinb[row * HD + d];
  ushort4 u1 = *(const ushort4*)(base + d);
  ushort4 u2 = *(const ushort4*)(base + d + 64);
  float x1[4] = {bf2f(u1.x), bf2f(u1.y), bf2f(u1.z), bf2f(u1.w)};
  float x2[4] = {bf2f(u2.x), bf2f(u2.y), bf2f(u2.z), bf2f(u2.w)};
  float cc[4] = {c.x, c.y, c.z, c.w};
  float ss[4] = {sn.x, sn.y, sn.z, sn.w};
  ushort4 o1, o2;
  o1.x = f2bf(x1[0] * cc[0] - x2[0] * ss[0]); o2.x = f2bf(x2[0] * cc[0] + x1[0] * ss[0]);
  o1.y = f2bf(x1[1] * cc[1] - x2[1] * ss[1]); o2.y = f2bf(x2[1] * cc[1] + x1[1] * ss[1]);
  o1.z = f2bf(x1[2] * cc[2] - x2[2] * ss[2]); o2.z = f2bf(x2[2] * cc[2] + x1[2] * ss[2]);
  o1.w = f2bf(x1[3] * cc[3] - x2[3] * ss[3]); o2.w = f2bf(x2[3] * cc[3] + x1[3] * ss[3]);
  *(ushort4*)(base + d) = o1;
  *(ushort4*)(base + d + 64) = o2;
}

// ---------------- V transpose: Vt[b][kv][d][s] = V[b][s][kv][d] ------------
__global__ __launch_bounds__(256)
void v_transpose(const __hip_bfloat16* __restrict__ QKV, __hip_bfloat16* __restrict__ Vt) {
  int i = blockIdx.x * 256 + threadIdx.x;
  int s = i & (SEQ - 1);
  int d = (i >> 11) & (HD - 1);
  int kv = (i >> 18) & 3;
  int b = i >> 20;
  Vt[i] = QKV[(size_t)(b * SEQ + s) * NQKV + HID + 512 + kv * HD + d];
}

// ---------------- Flash attention: 32x32 MFMA, in-register P ---------------
// 4 waves x 32 q-rows, KVBLK=64. Swapped QK^T: s = mfma_32x32(K, Q) ->
// lane l holds S^T[kv0+32s+(j&3)+8(j>>2)+4hf][q=qw+(l&31)], hf=l>>5.
// Softmax per-lane + one shfl_xor(32). PV B-frags built in-register:
// pack bf16 pairs, permlane32_swap (high(VDST)<->low(VSRC)) exchanges halves.
__global__ __launch_bounds__(256, 2)
void attn_fwd(const __hip_bfloat16* __restrict__ QKV, const __hip_bfloat16* __restrict__ Vt,
              __hip_bfloat16* __restrict__ AO) {
  const int qb = 15 - blockIdx.x;           // LPT: longest blocks first
  const int head = blockIdx.y;              // 0..27
  const int b = blockIdx.z;                 // 0..1
  const int kvh = head / GRP;
  const int tid = threadIdx.x;
  const int w = tid >> 6, l = tid & 63;
  const int q32 = l & 31;                   // lane's q within wave tile
  const int hf = l >> 5;                    // lane half
  const int qw = qb * 128 + w * 32;         // wave's first q row
  const float scl2 = 0.12751744055204955f;  // (1/sqrt(128)) * log2(e)
  const float NEGINF = -__builtin_inff();

  __shared__ __align__(16) __hip_bfloat16 Ks[2][64 * 128];   // 2x16 KB, swizzled
  __shared__ __align__(16) __hip_bfloat16 Vs[2][128 * 64];   // 2x16 KB, swizzled

  const char* Kb = (const char*)(QKV + (size_t)(b * SEQ) * NQKV + HID + kvh * HD);
  const char* Vb = (const char*)(Vt + (size_t)((b * NKVH + kvh) * HD) * SEQ);
  const __hip_bfloat16* Qb = QKV + (size_t)(b * SEQ + qw) * NQKV + head * HD;

  // Q fragments (B-operand, 32x32x16): qf[c] = Q[qw+q32][16c + 8hf + 0..7]
  bf16x8 qf[8];
#pragma unroll
  for (int c = 0; c < 8; c++)
    qf[c] = *(const bf16x8*)&Qb[(size_t)q32 * NQKV + c * 16 + 8 * hf];

  f32x16 of[4] = {};
  float mrow = -3e38f, lsum = 0.f;

  const int ntiles = 2 * qb + 2;

  auto stage = [&](int buf, int kv0) {
#pragma unroll
    for (int p = 0; p < 4; p++) {
      const int row = w * 16 + p * 4 + (l >> 4);      // K tile row (local)
      const int cb = (l & 15) * 16;
      gload_lds16(Kb + (size_t)(kv0 + row) * (NQKV * 2) + (cb ^ ((row & 7) << 4)),
                  (char*)(Ks[buf]) + w * 4096 + p * 1024);
    }
#pragma unroll
    for (int p = 0; p < 4; p++) {
      const int row = w * 32 + p * 8 + (l >> 3);      // V^T tile row (= d)
      const int cb = (l & 7) * 16;
      gload_lds16(Vb + (size_t)row * (SEQ * 2) + (size_t)kv0 * 2 + (cb ^ ((row & 7) << 4)),
                  (char*)(Vs[buf]) + w * 4096 + p * 1024);
    }
  };

  stage(0, 0);
  __syncthreads();

  const int swz = (q32 & 7) << 4;   // row&7 == q32&7 for all our LDS reads

  for (int t = 0; t < ntiles; t++) {
    const int kv0 = t * 64;
    const int cur = t & 1;
    if (t + 1 < ntiles) stage(cur ^ 1, kv0 + 64);    // prefetch under compute

    if (kv0 <= qw + 31) {
      const bool dos1 = (kv0 + 32 <= qw + 31);
      // ---- QK^T swapped, 32x32x16: A = K frag (row kv), B = Q frag (col q)
      f32x16 s0 = {}, s1 = {};
      const char* kb0 = (const char*)(Ks[cur]) + q32 * 256;
#pragma unroll
      for (int c = 0; c < 8; c++) {
        bf16x8 kf = *(const bf16x8*)(kb0 + ((c * 32 + 16 * hf) ^ swz));
        s0 = __builtin_amdgcn_mfma_f32_32x32x16_bf16(kf, qf[c], s0, 0, 0, 0);
      }
      if (dos1) {
        const char* kb1 = kb0 + 32 * 256;
#pragma unroll
        for (int c = 0; c < 8; c++) {
          bf16x8 kf = *(const bf16x8*)(kb1 + ((c * 32 + 16 * hf) ^ swz));
          s1 = __builtin_amdgcn_mfma_f32_32x32x16_bf16(kf, qf[c], s1, 0, 0, 0);
        }
      }

      // ---- mask + scale + per-lane max
      const int qg = qw + q32;
      float pmax = -3e38f;
      if (kv0 + 63 <= qw) {                 // interior tile: no mask
#pragma unroll
        for (int j = 0; j < 16; j++) {
          s0[j] *= scl2; pmax = fmaxf(pmax, s0[j]);
          s1[j] *= scl2; pmax = fmaxf(pmax, s1[j]);
        }
      } else {
#pragma unroll
        for (int j = 0; j < 16; j++) {
          const int kvl = (j & 3) + 8 * (j >> 2) + 4 * hf;
          s0[j] = (kv0 + kvl <= qg) ? s0[j] * scl2 : NEGINF;
          pmax = fmaxf(pmax, s0[j]);
        }
        if (dos1) {
#pragma unroll
          for (int j = 0; j < 16; j++) {
            const int kvl = (j & 3) + 8 * (j >> 2) + 4 * hf;
            s1[j] = (kv0 + 32 + kvl <= qg) ? s1[j] * scl2 : NEGINF;
            pmax = fmaxf(pmax, s1[j]);
          }
        }
      }
      pmax = fmaxf(pmax, __shfl_xor(pmax, 32));

      // ---- online softmax, defer-max (THR=11.5 in log2 domain)
      float rs = 0.f;
      if (__all(pmax - mrow <= 11.5f)) {
#pragma unroll
        for (int j = 0; j < 16; j++) { float p = exp2f(s0[j] - mrow); s0[j] = p; rs += p; }
        if (dos1) {
#pragma unroll
          for (int j = 0; j < 16; j++) { float p = exp2f(s1[j] - mrow); s1[j] = p; rs += p; }
        }
      } else {
        const float nm = fmaxf(mrow, pmax);
        const float al = exp2f(mrow - nm);
        mrow = nm;
#pragma unroll
        for (int j = 0; j < 16; j++) { float p = exp2f(s0[j] - nm); s0[j] = p; rs += p; }
        if (dos1) {
#pragma unroll
          for (int j = 0; j < 16; j++) { float p = exp2f(s1[j] - nm); s1[j] = p; rs += p; }
        }
        lsum *= al;
#pragma unroll
        for (int db = 0; db < 4; db++) of[db] *= al;
      }
      rs += __shfl_xor(rs, 32);
      lsum += rs;

      // ---- pack P pairs -> u32 words; permlane32_swap builds B-frags.
      // swap(A,B): ret[0]=[A_lo|B_lo], ret[1]=[A_hi|B_hi] (per 32-lane half).
      // B-frag t4 word order: {lo, lo, hi, hi} across the two swaps.
      int w0[8], w1[8];
#pragma unroll
      for (int k = 0; k < 8; k++)
        w0[k] = (int)((unsigned)f2bf(s0[2 * k]) | ((unsigned)f2bf(s0[2 * k + 1]) << 16));
      if (dos1) {
#pragma unroll
        for (int k = 0; k < 8; k++)
          w1[k] = (int)((unsigned)f2bf(s1[2 * k]) | ((unsigned)f2bf(s1[2 * k + 1]) << 16));
      }

      bf16x8 pB[4];
      {
        auto ra = __builtin_amdgcn_permlane32_swap(w0[0], w0[2], false, false);
        auto rb = __builtin_amdgcn_permlane32_swap(w0[1], w0[3], false, false);
        union { int4v i; bf16x8 h; } u;
        u.i = (int4v){(int)ra[0], (int)rb[0], (int)ra[1], (int)rb[1]};
        pB[0] = u.h;
        auto rc = __builtin_amdgcn_permlane32_swap(w0[4], w0[6], false, false);
        auto rd = __builtin_amdgcn_permlane32_swap(w0[5], w0[7], false, false);
        union { int4v i; bf16x8 h; } u2;
        u2.i = (int4v){(int)rc[0], (int)rd[0], (int)rc[1], (int)rd[1]};
        pB[1] = u2.h;
      }
      if (dos1) {
        auto ra = __builtin_amdgcn_permlane32_swap(w1[0], w1[2], false, false);
        auto rb = __builtin_amdgcn_permlane32_swap(w1[1], w1[3], false, false);
        union { int4v i; bf16x8 h; } u;
        u.i = (int4v){(int)ra[0], (int)rb[0], (int)ra[1], (int)rb[1]};
        pB[2] = u.h;
        auto rc = __builtin_amdgcn_permlane32_swap(w1[4], w1[6], false, false);
        auto rd = __builtin_amdgcn_permlane32_swap(w1[5], w1[7], false, false);
        union { int4v i; bf16x8 h; } u2;
        u2.i = (int4v){(int)rc[0], (int)rd[0], (int)rc[1], (int)rd[1]};
        pB[3] = u2.h;
      }

      // ---- PV (swapped): of = mfma_32x32(V^T frag, P frag)
      const int nt4 = dos1 ? 4 : 2;
#pragma unroll
      for (int db = 0; db < 4; db++) {
        const char* vp = (const char*)(Vs[cur]) + (db * 32 + q32) * 128;
#pragma unroll 4
        for (int t4 = 0; t4 < nt4; t4++) {
          bf16x8 vf = *(const bf16x8*)(vp + ((t4 * 32 + 16 * hf) ^ swz));
          of[db] = __builtin_amdgcn_mfma_f32_32x32x16_bf16(vf, pB[t4], of[db], 0, 0, 0);
        }
      }
    }
    __syncthreads();   // drains prefetch + guards buffer reuse
  }

  // ---- epilogue: of[db] reg j -> d = 32db + 8(j>>2) + 4hf + (j&3), q = qw+q32
  unsigned short* AOu = (unsigned short*)AO;
  const float inv = 1.0f / lsum;
  const size_t rowb = (size_t)(b * SEQ + qw + q32) * HID + head * HD;
#pragma unroll
  for (int db = 0; db < 4; db++) {
#pragma unroll
    for (int qd = 0; qd < 4; qd++) {
      ushort4 o;
      o.x = f2bf(of[db][4 * qd + 0] * inv);
      o.y = f2bf(of[db][4 * qd + 1] * inv);
      o.z = f2bf(of[db][4 * qd + 2] * inv);
      o.w = f2bf(of[db][4 * qd + 3] * inv);
      *(ushort4*)&AOu[rowb + db * 32 + 8 * qd + 4 * hf] = o;
    }
  }
}

// ---------------------------------------------------------------------------
extern "C" void kernel_launch(void* const* d_in, const int* in_sizes, int n_in,
                              void* d_out, int out_size, void* d_ws, size_t ws_size,
                              hipStream_t stream) {
  const float* hs = (const float*)d_in[0];
  const float* cosb = (const float*)d_in[1];
  const float* sinb = (const float*)d_in[2];
  const float* Wq = (const float*)d_in[3];
  const float* bq = (const float*)d_in[4];
  const float* Wk = (const float*)d_in[5];
  const float* bk = (const float*)d_in[6];
  const float* Wv = (const float*)d_in[7];
  const float* bv = (const float*)d_in[8];
  const float* Wo = (const float*)d_in[9];

  char* ws = (char*)d_ws;
  __hip_bfloat16* Xb = (__hip_bfloat16*)(ws);
  __hip_bfloat16* Wcat = (__hip_bfloat16*)(ws + 29360128);
  float* bcat = (float*)(ws + 62390272);
  __hip_bfloat16* QKVb = (__hip_bfloat16*)(ws + 62408704);
  __hip_bfloat16* Vt = (__hip_bfloat16*)(ws + 100157440);
  __hip_bfloat16* AOb = Xb;    // X dead after QKV GEMM
  __hip_bfloat16* Wob = Wcat;  // Wcat dead after QKV GEMM

  // Conversions to bf16
  cvt_f32_bf16<<<14336, 256, 0, stream>>>(hs, Xb, 3670016);                       // X
  cvt_f32_bf16<<<12544, 256, 0, stream>>>(Wq, Wcat, 3211264);                     // Wq rows 0..3583
  cvt_f32_bf16<<<1792, 256, 0, stream>>>(Wk, Wcat + (size_t)3584 * 3584, 458752); // Wk rows 3584..4095
  cvt_f32_bf16<<<1792, 256, 0, stream>>>(Wv, Wcat + (size_t)4096 * 3584, 458752); // Wv rows 4096..4607
  concat_bias<<<18, 256, 0, stream>>>(bq, bk, bv, bcat);

  // Fused QKV projection: [4096 x 3584] @ [4608 x 3584]^T + bias -> bf16
  gemm256<true, true><<<288, 512, 0, stream>>>(Xb, Wcat, bcat, QKVb, 4096, NQKV, HID, 16);

  // RoPE on Q + K head slots (in place, vectorized x4)
  rope_qk<<<8192, 256, 0, stream>>>(QKVb, cosb, sinb);

  // V transpose for PV fragment loads
  v_transpose<<<8192, 256, 0, stream>>>(QKVb, Vt);

  // Wo conversion (into the now-dead Wcat region)
  cvt_f32_bf16<<<12544, 256, 0, stream>>>(Wo, Wob, 3211264);

  // Flash attention: 128-row Q blocks, 4 waves x 32 rows, 64-col KV tiles
  dim3 ga(16, NHQ, 2);
  attn_fwd<<<ga, 256, 0, stream>>>(QKVb, Vt, AOb);

  // O projection -> f32 out
  gemm256<false, false><<<224, 512, 0, stream>>>(AOb, Wob, nullptr, d_out, 4096, HID, HID, 16);
}

// Round 10
// 657.885 us; speedup vs baseline: 6.1436x; 6.1436x over previous
//
#include <hip/hip_runtime.h>
#include <hip/hip_bf16.h>

// Qwen2 attention layer, MI355X/gfx950.
// B=2 S=2048 HID=3584 NH=28 NKV=4 D=128, causal, GQA groups=7.
// Round 10 (= round 9 + rule-#20 fix): PV B-fragments in NAMED registers
// (pB0..pB3) with statically-unrolled PV body — the runtime-bound pB[t4]
// loop in r9 sent the array to scratch (WRITE_SIZE 28->63 MB, 15x slowdown).
//
// Workspace layout (bytes), total ~99.5 MB:
//   Xb    @ 0          29,360,128  (B*S x HID bf16)      -> reused as AOb after QKV GEMM
//   Wcat  @ 29,360,128 33,030,144  (4608 x 3584 bf16)    -> reused as Wo-bf16 after QKV GEMM
//   bcat  @ 62,390,272 18,432      (4608 f32)
//   QKVb  @ 62,408,704 37,748,736  (B*S x 4608 bf16)
//   Vt    @ 100,157,440 4,194,304  (B*NKV*128 x S bf16)

#define HID   3584
#define NHQ   28
#define NKVH  4
#define HD    128
#define SEQ   2048
#define NQKV  4608
#define GRP   7

typedef __attribute__((ext_vector_type(8))) short bf16x8;
typedef __attribute__((ext_vector_type(4))) float f32x4;
typedef __attribute__((ext_vector_type(16))) float f32x16;
typedef __attribute__((ext_vector_type(4))) int int4v;

#define BARRIER() asm volatile("s_barrier" ::: "memory")

__device__ __forceinline__ void gload_lds16(const void* g, void* l) {
  __builtin_amdgcn_global_load_lds(
      (const __attribute__((address_space(1))) void*)g,
      (__attribute__((address_space(3))) void*)l, 16, 0, 0);
}

__device__ __forceinline__ unsigned short f2bf(float f) {
  __hip_bfloat16 h = __float2bfloat16(f);
  return *reinterpret_cast<unsigned short*>(&h);
}

__device__ __forceinline__ float bf2f(unsigned short u) {
  __hip_bfloat16 h = *reinterpret_cast<__hip_bfloat16*>(&u);
  return __bfloat162float(h);
}

// ---------------- f32 -> bf16 conversion (vectorized, 4 elems/thread) ------
__global__ __launch_bounds__(256)
void cvt_f32_bf16(const float* __restrict__ src, __hip_bfloat16* __restrict__ dst, int n4) {
  int i = blockIdx.x * 256 + threadIdx.x;
  if (i >= n4) return;
  float4 v = ((const float4*)src)[i];
  ushort4 o;
  o.x = f2bf(v.x); o.y = f2bf(v.y); o.z = f2bf(v.z); o.w = f2bf(v.w);
  ((ushort4*)dst)[i] = o;
}

__global__ __launch_bounds__(256)
void concat_bias(const float* __restrict__ bq, const float* __restrict__ bk,
                 const float* __restrict__ bv, float* __restrict__ out) {
  int i = blockIdx.x * 256 + threadIdx.x;
  if (i < HID) out[i] = bq[i];
  else if (i < HID + 512) out[i] = bk[i - HID];
  else if (i < NQKV) out[i] = bv[i - HID - 512];
}

// ---------------- GEMM: C[M][N] = A[M][K] * B[N][K]^T (+bias) --------------
// 256x256 tile, BK=64, 8 waves, dbuf LDS, 8-phase counted-vmcnt schedule.
// 1D grid with bijective XCD swizzle (m204).
template<bool HAS_BIAS, bool OUT_BF16>
__global__ __launch_bounds__(512, 2)
void gemm256(const __hip_bfloat16* __restrict__ A, const __hip_bfloat16* __restrict__ Bm,
             const float* __restrict__ bias, void* __restrict__ Cv,
             int M, int N, int K, int nmt) {
  __shared__ __align__(16) char lds[131072];
  const int tid = threadIdx.x;
  const int w = tid >> 6, l = tid & 63;
  const int g = l >> 4, r = l & 15;
  const int wr = w >> 2, wc = w & 3;

  // bijective XCD swizzle (nwg % 8 == 0 for both our grids)
  const int nwg = gridDim.x;
  const int qq = nwg >> 3, r8 = nwg & 7;
  const int xcd = blockIdx.x & 7, idx = blockIdx.x >> 3;
  const int wgid = (xcd < r8 ? xcd * (qq + 1) : r8 * (qq + 1) + (xcd - r8) * qq) + idx;
  const int bm = (wgid % nmt) * 256, bn = (wgid / nmt) * 256;

  const int NKT = K >> 6;
  const size_t Kb2 = (size_t)K * 2;
  const int swz = (r & 7) << 4;

  auto issueHalf = [&](int kt, int h) {
    const char* src = (h < 2) ? (const char*)A : (const char*)Bm;
    const int rbase = (h < 2) ? bm : bn;
    char* reg = lds + (kt & 1) * 65536 + ((h < 2) ? 0 : 32768);
#pragma unroll
    for (int i = 0; i < 2; ++i) {
      const int lrow = (h & 1) * 128 + w * 16 + i * 8;   // wave-uniform dest row
      const int row = lrow + (l >> 3);                    // per-lane source row
      const int cb = (l & 7) * 16;
      gload_lds16(src + (size_t)(rbase + row) * Kb2 + (size_t)kt * 128 + (cb ^ ((row & 7) << 4)),
                  reg + lrow * 128);
    }
  };

  auto ldA = [&](int d, int mf, int kk) -> bf16x8 {
    const int row = wr * 128 + mf * 16 + r;
    return *(const bf16x8*)(lds + d * 65536 + row * 128 + ((kk * 64 + g * 16) ^ swz));
  };
  auto ldB = [&](int d, int nf, int kk) -> bf16x8 {
    const int row = wc * 64 + nf * 16 + r;
    return *(const bf16x8*)(lds + d * 65536 + 32768 + row * 128 + ((kk * 64 + g * 16) ^ swz));
  };

  f32x4 acc[8][4];
#pragma unroll
  for (int m = 0; m < 8; m++)
#pragma unroll
    for (int n = 0; n < 4; n++) acc[m][n] = (f32x4){0.f, 0.f, 0.f, 0.f};

#pragma unroll
  for (int h = 0; h < 4; ++h) issueHalf(0, h);
#pragma unroll
  for (int h = 0; h < 4; ++h) issueHalf(1, h);
  asm volatile("s_waitcnt vmcnt(8)" ::: "memory");
  BARRIER();

  bf16x8 af[4][2], bfr[4][2];

#pragma unroll 1
  for (int kt = 0; kt < NKT; ++kt) {
    const int d = kt & 1;

    if (kt >= 1 && kt + 1 < NKT) { issueHalf(kt + 1, 1); issueHalf(kt + 1, 3); }
#pragma unroll
    for (int mf = 0; mf < 4; mf++)
#pragma unroll
      for (int kk = 0; kk < 2; kk++) af[mf][kk] = ldA(d, mf, kk);
#pragma unroll
    for (int nf = 0; nf < 2; nf++)
#pragma unroll
      for (int kk = 0; kk < 2; kk++) bfr[nf][kk] = ldB(d, nf, kk);
    BARRIER();
    __builtin_amdgcn_s_setprio(1);
#pragma unroll
    for (int mf = 0; mf < 4; mf++)
#pragma unroll
      for (int nf = 0; nf < 2; nf++)
#pragma unroll
        for (int kk = 0; kk < 2; kk++)
          acc[mf][nf] = __builtin_amdgcn_mfma_f32_16x16x32_bf16(af[mf][kk], bfr[nf][kk], acc[mf][nf], 0, 0, 0);
    __builtin_amdgcn_s_setprio(0);
    BARRIER();

#pragma unroll
    for (int nf = 2; nf < 4; nf++)
#pragma unroll
      for (int kk = 0; kk < 2; kk++) bfr[nf][kk] = ldB(d, nf, kk);
    BARRIER();
    __builtin_amdgcn_s_setprio(1);
#pragma unroll
    for (int mf = 0; mf < 4; mf++)
#pragma unroll
      for (int nf = 2; nf < 4; nf++)
#pragma unroll
        for (int kk = 0; kk < 2; kk++)
          acc[mf][nf] = __builtin_amdgcn_mfma_f32_16x16x32_bf16(af[mf][kk], bfr[nf][kk], acc[mf][nf], 0, 0, 0);
    __builtin_amdgcn_s_setprio(0);
    BARRIER();

    if (kt + 2 < NKT) issueHalf(kt + 2, 2);
#pragma unroll
    for (int mf = 0; mf < 4; mf++)
#pragma unroll
      for (int kk = 0; kk < 2; kk++) af[mf][kk] = ldA(d, mf + 4, kk);
    BARRIER();
    __builtin_amdgcn_s_setprio(1);
#pragma unroll
    for (int mf = 0; mf < 4; mf++)
#pragma unroll
      for (int nf = 0; nf < 2; nf++)
#pragma unroll
        for (int kk = 0; kk < 2; kk++)
          acc[mf + 4][nf] = __builtin_amdgcn_mfma_f32_16x16x32_bf16(af[mf][kk], bfr[nf][kk], acc[mf + 4][nf], 0, 0, 0);
    __builtin_amdgcn_s_setprio(0);
    BARRIER();

    if (kt + 2 < NKT) {
      issueHalf(kt + 2, 0);
      asm volatile("s_waitcnt vmcnt(4)" ::: "memory");
    } else if (kt + 1 < NKT) {
      asm volatile("s_waitcnt vmcnt(0)" ::: "memory");
    }
    BARRIER();
    __builtin_amdgcn_s_setprio(1);
#pragma unroll
    for (int mf = 0; mf < 4; mf++)
#pragma unroll
      for (int nf = 2; nf < 4; nf++)
#pragma unroll
        for (int kk = 0; kk < 2; kk++)
          acc[mf + 4][nf] = __builtin_amdgcn_mfma_f32_16x16x32_bf16(af[mf][kk], bfr[nf][kk], acc[mf + 4][nf], 0, 0, 0);
    __builtin_amdgcn_s_setprio(0);
    BARRIER();
  }

#pragma unroll
  for (int nf = 0; nf < 4; nf++) {
    const int gcol = bn + wc * 64 + nf * 16 + r;
    const float bv = HAS_BIAS ? bias[gcol] : 0.f;
#pragma unroll
    for (int mf = 0; mf < 8; mf++) {
#pragma unroll
      for (int j = 0; j < 4; j++) {
        const int grow = bm + wr * 128 + mf * 16 + 4 * g + j;
        float v = acc[mf][nf][j] + bv;
        if constexpr (OUT_BF16)
          ((__hip_bfloat16*)Cv)[(size_t)grow * N + gcol] = __float2bfloat16(v);
        else
          ((float*)Cv)[(size_t)grow * N + gcol] = v;
      }
    }
  }
}

// ---------------- RoPE on Q and K head slots (in-place, bf16, x4 vec) ------
__global__ __launch_bounds__(256)
void rope_qk(__hip_bfloat16* __restrict__ QKV, const float* __restrict__ cosb,
             const float* __restrict__ sinb) {
  int i = blockIdx.x * 256 + threadIdx.x;   // 2,097,152 threads
  int d = (i & 15) * 4;
  int hh = (i >> 4) & 31;
  int row = i >> 9;
  int cb = (hh < NHQ) ? hh * HD : HID + (hh - NHQ) * HD;
  unsigned short* base = (unsigned short*)QKV + (size_t)row * NQKV + cb;
  float4 c = *(const float4*)&cosb[row * HD + d];
  float4 sn = *(const float4*)&sinb[row * HD + d];
  ushort4 u1 = *(const ushort4*)(base + d);
  ushort4 u2 = *(const ushort4*)(base + d + 64);
  float x1[4] = {bf2f(u1.x), bf2f(u1.y), bf2f(u1.z), bf2f(u1.w)};
  float x2[4] = {bf2f(u2.x), bf2f(u2.y), bf2f(u2.z), bf2f(u2.w)};
  float cc[4] = {c.x, c.y, c.z, c.w};
  float ss[4] = {sn.x, sn.y, sn.z, sn.w};
  ushort4 o1, o2;
  o1.x = f2bf(x1[0] * cc[0] - x2[0] * ss[0]); o2.x = f2bf(x2[0] * cc[0] + x1[0] * ss[0]);
  o1.y = f2bf(x1[1] * cc[1] - x2[1] * ss[1]); o2.y = f2bf(x2[1] * cc[1] + x1[1] * ss[1]);
  o1.z = f2bf(x1[2] * cc[2] - x2[2] * ss[2]); o2.z = f2bf(x2[2] * cc[2] + x1[2] * ss[2]);
  o1.w = f2bf(x1[3] * cc[3] - x2[3] * ss[3]); o2.w = f2bf(x2[3] * cc[3] + x1[3] * ss[3]);
  *(ushort4*)(base + d) = o1;
  *(ushort4*)(base + d + 64) = o2;
}

// ---------------- V transpose: Vt[b][kv][d][s] = V[b][s][kv][d] ------------
__global__ __launch_bounds__(256)
void v_transpose(const __hip_bfloat16* __restrict__ QKV, __hip_bfloat16* __restrict__ Vt) {
  int i = blockIdx.x * 256 + threadIdx.x;
  int s = i & (SEQ - 1);
  int d = (i >> 11) & (HD - 1);
  int kv = (i >> 18) & 3;
  int b = i >> 20;
  Vt[i] = QKV[(size_t)(b * SEQ + s) * NQKV + HID + 512 + kv * HD + d];
}

// ---------------- Flash attention: 32x32 MFMA, in-register P ---------------
// 4 waves x 32 q-rows, KVBLK=64. Swapped QK^T: s = mfma_32x32(K, Q) ->
// lane l holds S^T[kv0+32s+(j&3)+8(j>>2)+4hf][q=qw+(l&31)], hf=l>>5.
// Softmax per-lane + one shfl_xor(32). PV B-frags in NAMED registers via
// permlane32_swap (high(VDST)<->low(VSRC)); statically unrolled PV.
__global__ __launch_bounds__(256, 2)
void attn_fwd(const __hip_bfloat16* __restrict__ QKV, const __hip_bfloat16* __restrict__ Vt,
              __hip_bfloat16* __restrict__ AO) {
  const int qb = 15 - blockIdx.x;           // LPT: longest blocks first
  const int head = blockIdx.y;              // 0..27
  const int b = blockIdx.z;                 // 0..1
  const int kvh = head / GRP;
  const int tid = threadIdx.x;
  const int w = tid >> 6, l = tid & 63;
  const int q32 = l & 31;                   // lane's q within wave tile
  const int hf = l >> 5;                    // lane half
  const int qw = qb * 128 + w * 32;         // wave's first q row
  const float scl2 = 0.12751744055204955f;  // (1/sqrt(128)) * log2(e)
  const float NEGINF = -__builtin_inff();

  __shared__ __align__(16) __hip_bfloat16 Ks[2][64 * 128];   // 2x16 KB, swizzled
  __shared__ __align__(16) __hip_bfloat16 Vs[2][128 * 64];   // 2x16 KB, swizzled

  const char* Kb = (const char*)(QKV + (size_t)(b * SEQ) * NQKV + HID + kvh * HD);
  const char* Vb = (const char*)(Vt + (size_t)((b * NKVH + kvh) * HD) * SEQ);
  const __hip_bfloat16* Qb = QKV + (size_t)(b * SEQ + qw) * NQKV + head * HD;

  // Q fragments (B-operand, 32x32x16): qf[c] = Q[qw+q32][16c + 8hf + 0..7]
  bf16x8 qf[8];
#pragma unroll
  for (int c = 0; c < 8; c++)
    qf[c] = *(const bf16x8*)&Qb[(size_t)q32 * NQKV + c * 16 + 8 * hf];

  f32x16 of[4] = {};
  float mrow = -3e38f, lsum = 0.f;

  const int ntiles = 2 * qb + 2;

  auto stage = [&](int buf, int kv0) {
#pragma unroll
    for (int p = 0; p < 4; p++) {
      const int row = w * 16 + p * 4 + (l >> 4);      // K tile row (local)
      const int cb = (l & 15) * 16;
      gload_lds16(Kb + (size_t)(kv0 + row) * (NQKV * 2) + (cb ^ ((row & 7) << 4)),
                  (char*)(Ks[buf]) + w * 4096 + p * 1024);
    }
#pragma unroll
    for (int p = 0; p < 4; p++) {
      const int row = w * 32 + p * 8 + (l >> 3);      // V^T tile row (= d)
      const int cb = (l & 7) * 16;
      gload_lds16(Vb + (size_t)row * (SEQ * 2) + (size_t)kv0 * 2 + (cb ^ ((row & 7) << 4)),
                  (char*)(Vs[buf]) + w * 4096 + p * 1024);
    }
  };

  stage(0, 0);
  __syncthreads();

  const int swz = (q32 & 7) << 4;   // row&7 == q32&7 for all our LDS reads

  for (int t = 0; t < ntiles; t++) {
    const int kv0 = t * 64;
    const int cur = t & 1;
    if (t + 1 < ntiles) stage(cur ^ 1, kv0 + 64);    // prefetch under compute

    if (kv0 <= qw + 31) {
      const bool dos1 = (kv0 + 32 <= qw + 31);
      // ---- QK^T swapped, 32x32x16: A = K frag (row kv), B = Q frag (col q)
      f32x16 s0 = {}, s1 = {};
      const char* kb0 = (const char*)(Ks[cur]) + q32 * 256;
#pragma unroll
      for (int c = 0; c < 8; c++) {
        bf16x8 kf = *(const bf16x8*)(kb0 + ((c * 32 + 16 * hf) ^ swz));
        s0 = __builtin_amdgcn_mfma_f32_32x32x16_bf16(kf, qf[c], s0, 0, 0, 0);
      }
      if (dos1) {
        const char* kb1 = kb0 + 32 * 256;
#pragma unroll
        for (int c = 0; c < 8; c++) {
          bf16x8 kf = *(const bf16x8*)(kb1 + ((c * 32 + 16 * hf) ^ swz));
          s1 = __builtin_amdgcn_mfma_f32_32x32x16_bf16(kf, qf[c], s1, 0, 0, 0);
        }
      }

      // ---- mask + scale + per-lane max
      const int qg = qw + q32;
      float pmax = -3e38f;
      if (kv0 + 63 <= qw) {                 // interior tile: no mask
#pragma unroll
        for (int j = 0; j < 16; j++) {
          s0[j] *= scl2; pmax = fmaxf(pmax, s0[j]);
          s1[j] *= scl2; pmax = fmaxf(pmax, s1[j]);
        }
      } else {
#pragma unroll
        for (int j = 0; j < 16; j++) {
          const int kvl = (j & 3) + 8 * (j >> 2) + 4 * hf;
          s0[j] = (kv0 + kvl <= qg) ? s0[j] * scl2 : NEGINF;
          pmax = fmaxf(pmax, s0[j]);
        }
        if (dos1) {
#pragma unroll
          for (int j = 0; j < 16; j++) {
            const int kvl = (j & 3) + 8 * (j >> 2) + 4 * hf;
            s1[j] = (kv0 + 32 + kvl <= qg) ? s1[j] * scl2 : NEGINF;
            pmax = fmaxf(pmax, s1[j]);
          }
        }
      }
      pmax = fmaxf(pmax, __shfl_xor(pmax, 32));

      // ---- online softmax, defer-max (THR=11.5 in log2 domain)
      float rs = 0.f;
      if (__all(pmax - mrow <= 11.5f)) {
#pragma unroll
        for (int j = 0; j < 16; j++) { float p = exp2f(s0[j] - mrow); s0[j] = p; rs += p; }
        if (dos1) {
#pragma unroll
          for (int j = 0; j < 16; j++) { float p = exp2f(s1[j] - mrow); s1[j] = p; rs += p; }
        }
      } else {
        const float nm = fmaxf(mrow, pmax);
        const float al = exp2f(mrow - nm);
        mrow = nm;
#pragma unroll
        for (int j = 0; j < 16; j++) { float p = exp2f(s0[j] - nm); s0[j] = p; rs += p; }
        if (dos1) {
#pragma unroll
          for (int j = 0; j < 16; j++) { float p = exp2f(s1[j] - nm); s1[j] = p; rs += p; }
        }
        lsum *= al;
#pragma unroll
        for (int db = 0; db < 4; db++) of[db] *= al;
      }
      rs += __shfl_xor(rs, 32);
      lsum += rs;

      // ---- pack P pairs -> u32 words; permlane32_swap builds B-frags.
      // swap(A,B): ret[0]=[A_lo|B_lo], ret[1]=[A_hi|B_hi] (per 32-lane half).
      int w0[8], w1[8];
#pragma unroll
      for (int k = 0; k < 8; k++)
        w0[k] = (int)((unsigned)f2bf(s0[2 * k]) | ((unsigned)f2bf(s0[2 * k + 1]) << 16));
      if (dos1) {
#pragma unroll
        for (int k = 0; k < 8; k++)
          w1[k] = (int)((unsigned)f2bf(s1[2 * k]) | ((unsigned)f2bf(s1[2 * k + 1]) << 16));
      }

      bf16x8 pB0, pB1, pB2, pB3;   // NAMED regs (rule #20: no runtime idx)
      {
        auto ra = __builtin_amdgcn_permlane32_swap(w0[0], w0[2], false, false);
        auto rb = __builtin_amdgcn_permlane32_swap(w0[1], w0[3], false, false);
        union { int4v i; bf16x8 h; } u;
        u.i = (int4v){(int)ra[0], (int)rb[0], (int)ra[1], (int)rb[1]};
        pB0 = u.h;
        auto rc = __builtin_amdgcn_permlane32_swap(w0[4], w0[6], false, false);
        auto rd = __builtin_amdgcn_permlane32_swap(w0[5], w0[7], false, false);
        union { int4v i; bf16x8 h; } u2;
        u2.i = (int4v){(int)rc[0], (int)rd[0], (int)rc[1], (int)rd[1]};
        pB1 = u2.h;
      }
      if (dos1) {
        auto ra = __builtin_amdgcn_permlane32_swap(w1[0], w1[2], false, false);
        auto rb = __builtin_amdgcn_permlane32_swap(w1[1], w1[3], false, false);
        union { int4v i; bf16x8 h; } u;
        u.i = (int4v){(int)ra[0], (int)rb[0], (int)ra[1], (int)rb[1]};
        pB2 = u.h;
        auto rc = __builtin_amdgcn_permlane32_swap(w1[4], w1[6], false, false);
        auto rd = __builtin_amdgcn_permlane32_swap(w1[5], w1[7], false, false);
        union { int4v i; bf16x8 h; } u2;
        u2.i = (int4v){(int)rc[0], (int)rd[0], (int)rc[1], (int)rd[1]};
        pB3 = u2.h;
      }

      // ---- PV (swapped): of = mfma_32x32(V^T frag, P frag); static unroll
#pragma unroll
      for (int db = 0; db < 4; db++) {
        const char* vp = (const char*)(Vs[cur]) + (db * 32 + q32) * 128;
        bf16x8 vf0 = *(const bf16x8*)(vp + ((0 * 32 + 16 * hf) ^ swz));
        of[db] = __builtin_amdgcn_mfma_f32_32x32x16_bf16(vf0, pB0, of[db], 0, 0, 0);
        bf16x8 vf1 = *(const bf16x8*)(vp + ((1 * 32 + 16 * hf) ^ swz));
        of[db] = __builtin_amdgcn_mfma_f32_32x32x16_bf16(vf1, pB1, of[db], 0, 0, 0);
        if (dos1) {
          bf16x8 vf2 = *(const bf16x8*)(vp + ((2 * 32 + 16 * hf) ^ swz));
          of[db] = __builtin_amdgcn_mfma_f32_32x32x16_bf16(vf2, pB2, of[db], 0, 0, 0);
          bf16x8 vf3 = *(const bf16x8*)(vp + ((3 * 32 + 16 * hf) ^ swz));
          of[db] = __builtin_amdgcn_mfma_f32_32x32x16_bf16(vf3, pB3, of[db], 0, 0, 0);
        }
      }
    }
    __syncthreads();   // drains prefetch + guards buffer reuse
  }

  // ---- epilogue: of[db] reg j -> d = 32db + 8(j>>2) + 4hf + (j&3), q = qw+q32
  unsigned short* AOu = (unsigned short*)AO;
  const float inv = 1.0f / lsum;
  const size_t rowb = (size_t)(b * SEQ + qw + q32) * HID + head * HD;
#pragma unroll
  for (int db = 0; db < 4; db++) {
#pragma unroll
    for (int qd = 0; qd < 4; qd++) {
      ushort4 o;
      o.x = f2bf(of[db][4 * qd + 0] * inv);
      o.y = f2bf(of[db][4 * qd + 1] * inv);
      o.z = f2bf(of[db][4 * qd + 2] * inv);
      o.w = f2bf(of[db][4 * qd + 3] * inv);
      *(ushort4*)&AOu[rowb + db * 32 + 8 * qd + 4 * hf] = o;
    }
  }
}

// ---------------------------------------------------------------------------
extern "C" void kernel_launch(void* const* d_in, const int* in_sizes, int n_in,
                              void* d_out, int out_size, void* d_ws, size_t ws_size,
                              hipStream_t stream) {
  const float* hs = (const float*)d_in[0];
  const float* cosb = (const float*)d_in[1];
  const float* sinb = (const float*)d_in[2];
  const float* Wq = (const float*)d_in[3];
  const float* bq = (const float*)d_in[4];
  const float* Wk = (const float*)d_in[5];
  const float* bk = (const float*)d_in[6];
  const float* Wv = (const float*)d_in[7];
  const float* bv = (const float*)d_in[8];
  const float* Wo = (const float*)d_in[9];

  char* ws = (char*)d_ws;
  __hip_bfloat16* Xb = (__hip_bfloat16*)(ws);
  __hip_bfloat16* Wcat = (__hip_bfloat16*)(ws + 29360128);
  float* bcat = (float*)(ws + 62390272);
  __hip_bfloat16* QKVb = (__hip_bfloat16*)(ws + 62408704);
  __hip_bfloat16* Vt = (__hip_bfloat16*)(ws + 100157440);
  __hip_bfloat16* AOb = Xb;    // X dead after QKV GEMM
  __hip_bfloat16* Wob = Wcat;  // Wcat dead after QKV GEMM

  // Conversions to bf16
  cvt_f32_bf16<<<14336, 256, 0, stream>>>(hs, Xb, 3670016);                       // X
  cvt_f32_bf16<<<12544, 256, 0, stream>>>(Wq, Wcat, 3211264);                     // Wq rows 0..3583
  cvt_f32_bf16<<<1792, 256, 0, stream>>>(Wk, Wcat + (size_t)3584 * 3584, 458752); // Wk rows 3584..4095
  cvt_f32_bf16<<<1792, 256, 0, stream>>>(Wv, Wcat + (size_t)4096 * 3584, 458752); // Wv rows 4096..4607
  concat_bias<<<18, 256, 0, stream>>>(bq, bk, bv, bcat);

  // Fused QKV projection: [4096 x 3584] @ [4608 x 3584]^T + bias -> bf16
  gemm256<true, true><<<288, 512, 0, stream>>>(Xb, Wcat, bcat, QKVb, 4096, NQKV, HID, 16);

  // RoPE on Q + K head slots (in place, vectorized x4)
  rope_qk<<<8192, 256, 0, stream>>>(QKVb, cosb, sinb);

  // V transpose for PV fragment loads
  v_transpose<<<8192, 256, 0, stream>>>(QKVb, Vt);

  // Wo conversion (into the now-dead Wcat region)
  cvt_f32_bf16<<<12544, 256, 0, stream>>>(Wo, Wob, 3211264);

  // Flash attention: 128-row Q blocks, 4 waves x 32 rows, 64-col KV tiles
  dim3 ga(16, NHQ, 2);
  attn_fwd<<<ga, 256, 0, stream>>>(QKVb, Vt, AOb);

  // O projection -> f32 out
  gemm256<false, false><<<224, 512, 0, stream>>>(AOb, Wob, nullptr, d_out, 4096, HID, HID, 16);
}

// Round 11
// 587.083 us; speedup vs baseline: 6.8845x; 1.1206x over previous
//
#include <hip/hip_runtime.h>
#include <hip/hip_bf16.h>

// Qwen2 attention layer, MI355X/gfx950.
// B=2 S=2048 HID=3584 NH=28 NKV=4 D=128, causal, GQA groups=7.
// Round 11: spill elimination in attn. KVBLK=64 staging kept, but compute
// streams in 32-col passes: one f32x16 S-tile + one wv[8] live at a time,
// pB built transiently per t4 right before its PV sweep. Deletes s1/w1
// (~45 regs of peak live state) -> no scratch (r10 had 128 B/thread spill:
// WRITE_SIZE 56 MB vs 28.7 MB AO baseline).
//
// Workspace layout (bytes), total ~99.5 MB:
//   Xb    @ 0          29,360,128  (B*S x HID bf16)      -> reused as AOb after QKV GEMM
//   Wcat  @ 29,360,128 33,030,144  (4608 x 3584 bf16)    -> reused as Wo-bf16 after QKV GEMM
//   bcat  @ 62,390,272 18,432      (4608 f32)
//   QKVb  @ 62,408,704 37,748,736  (B*S x 4608 bf16)
//   Vt    @ 100,157,440 4,194,304  (B*NKV*128 x S bf16)

#define HID   3584
#define NHQ   28
#define NKVH  4
#define HD    128
#define SEQ   2048
#define NQKV  4608
#define GRP   7

typedef __attribute__((ext_vector_type(8))) short bf16x8;
typedef __attribute__((ext_vector_type(4))) float f32x4;
typedef __attribute__((ext_vector_type(16))) float f32x16;
typedef __attribute__((ext_vector_type(4))) int int4v;

#define BARRIER() asm volatile("s_barrier" ::: "memory")

__device__ __forceinline__ void gload_lds16(const void* g, void* l) {
  __builtin_amdgcn_global_load_lds(
      (const __attribute__((address_space(1))) void*)g,
      (__attribute__((address_space(3))) void*)l, 16, 0, 0);
}

__device__ __forceinline__ unsigned short f2bf(float f) {
  __hip_bfloat16 h = __float2bfloat16(f);
  return *reinterpret_cast<unsigned short*>(&h);
}

__device__ __forceinline__ float bf2f(unsigned short u) {
  __hip_bfloat16 h = *reinterpret_cast<__hip_bfloat16*>(&u);
  return __bfloat162float(h);
}

// ---------------- f32 -> bf16 conversion (vectorized, 4 elems/thread) ------
__global__ __launch_bounds__(256)
void cvt_f32_bf16(const float* __restrict__ src, __hip_bfloat16* __restrict__ dst, int n4) {
  int i = blockIdx.x * 256 + threadIdx.x;
  if (i >= n4) return;
  float4 v = ((const float4*)src)[i];
  ushort4 o;
  o.x = f2bf(v.x); o.y = f2bf(v.y); o.z = f2bf(v.z); o.w = f2bf(v.w);
  ((ushort4*)dst)[i] = o;
}

__global__ __launch_bounds__(256)
void concat_bias(const float* __restrict__ bq, const float* __restrict__ bk,
                 const float* __restrict__ bv, float* __restrict__ out) {
  int i = blockIdx.x * 256 + threadIdx.x;
  if (i < HID) out[i] = bq[i];
  else if (i < HID + 512) out[i] = bk[i - HID];
  else if (i < NQKV) out[i] = bv[i - HID - 512];
}

// ---------------- GEMM: C[M][N] = A[M][K] * B[N][K]^T (+bias) --------------
// 256x256 tile, BK=64, 8 waves, dbuf LDS, 8-phase counted-vmcnt schedule.
// 1D grid with bijective XCD swizzle (m204).
template<bool HAS_BIAS, bool OUT_BF16>
__global__ __launch_bounds__(512, 2)
void gemm256(const __hip_bfloat16* __restrict__ A, const __hip_bfloat16* __restrict__ Bm,
             const float* __restrict__ bias, void* __restrict__ Cv,
             int M, int N, int K, int nmt) {
  __shared__ __align__(16) char lds[131072];
  const int tid = threadIdx.x;
  const int w = tid >> 6, l = tid & 63;
  const int g = l >> 4, r = l & 15;
  const int wr = w >> 2, wc = w & 3;

  // bijective XCD swizzle (nwg % 8 == 0 for both our grids)
  const int nwg = gridDim.x;
  const int qq = nwg >> 3, r8 = nwg & 7;
  const int xcd = blockIdx.x & 7, idx = blockIdx.x >> 3;
  const int wgid = (xcd < r8 ? xcd * (qq + 1) : r8 * (qq + 1) + (xcd - r8) * qq) + idx;
  const int bm = (wgid % nmt) * 256, bn = (wgid / nmt) * 256;

  const int NKT = K >> 6;
  const size_t Kb2 = (size_t)K * 2;
  const int swz = (r & 7) << 4;

  auto issueHalf = [&](int kt, int h) {
    const char* src = (h < 2) ? (const char*)A : (const char*)Bm;
    const int rbase = (h < 2) ? bm : bn;
    char* reg = lds + (kt & 1) * 65536 + ((h < 2) ? 0 : 32768);
#pragma unroll
    for (int i = 0; i < 2; ++i) {
      const int lrow = (h & 1) * 128 + w * 16 + i * 8;   // wave-uniform dest row
      const int row = lrow + (l >> 3);                    // per-lane source row
      const int cb = (l & 7) * 16;
      gload_lds16(src + (size_t)(rbase + row) * Kb2 + (size_t)kt * 128 + (cb ^ ((row & 7) << 4)),
                  reg + lrow * 128);
    }
  };

  auto ldA = [&](int d, int mf, int kk) -> bf16x8 {
    const int row = wr * 128 + mf * 16 + r;
    return *(const bf16x8*)(lds + d * 65536 + row * 128 + ((kk * 64 + g * 16) ^ swz));
  };
  auto ldB = [&](int d, int nf, int kk) -> bf16x8 {
    const int row = wc * 64 + nf * 16 + r;
    return *(const bf16x8*)(lds + d * 65536 + 32768 + row * 128 + ((kk * 64 + g * 16) ^ swz));
  };

  f32x4 acc[8][4];
#pragma unroll
  for (int m = 0; m < 8; m++)
#pragma unroll
    for (int n = 0; n < 4; n++) acc[m][n] = (f32x4){0.f, 0.f, 0.f, 0.f};

#pragma unroll
  for (int h = 0; h < 4; ++h) issueHalf(0, h);
#pragma unroll
  for (int h = 0; h < 4; ++h) issueHalf(1, h);
  asm volatile("s_waitcnt vmcnt(8)" ::: "memory");
  BARRIER();

  bf16x8 af[4][2], bfr[4][2];

#pragma unroll 1
  for (int kt = 0; kt < NKT; ++kt) {
    const int d = kt & 1;

    if (kt >= 1 && kt + 1 < NKT) { issueHalf(kt + 1, 1); issueHalf(kt + 1, 3); }
#pragma unroll
    for (int mf = 0; mf < 4; mf++)
#pragma unroll
      for (int kk = 0; kk < 2; kk++) af[mf][kk] = ldA(d, mf, kk);
#pragma unroll
    for (int nf = 0; nf < 2; nf++)
#pragma unroll
      for (int kk = 0; kk < 2; kk++) bfr[nf][kk] = ldB(d, nf, kk);
    BARRIER();
    __builtin_amdgcn_s_setprio(1);
#pragma unroll
    for (int mf = 0; mf < 4; mf++)
#pragma unroll
      for (int nf = 0; nf < 2; nf++)
#pragma unroll
        for (int kk = 0; kk < 2; kk++)
          acc[mf][nf] = __builtin_amdgcn_mfma_f32_16x16x32_bf16(af[mf][kk], bfr[nf][kk], acc[mf][nf], 0, 0, 0);
    __builtin_amdgcn_s_setprio(0);
    BARRIER();

#pragma unroll
    for (int nf = 2; nf < 4; nf++)
#pragma unroll
      for (int kk = 0; kk < 2; kk++) bfr[nf][kk] = ldB(d, nf, kk);
    BARRIER();
    __builtin_amdgcn_s_setprio(1);
#pragma unroll
    for (int mf = 0; mf < 4; mf++)
#pragma unroll
      for (int nf = 2; nf < 4; nf++)
#pragma unroll
        for (int kk = 0; kk < 2; kk++)
          acc[mf][nf] = __builtin_amdgcn_mfma_f32_16x16x32_bf16(af[mf][kk], bfr[nf][kk], acc[mf][nf], 0, 0, 0);
    __builtin_amdgcn_s_setprio(0);
    BARRIER();

    if (kt + 2 < NKT) issueHalf(kt + 2, 2);
#pragma unroll
    for (int mf = 0; mf < 4; mf++)
#pragma unroll
      for (int kk = 0; kk < 2; kk++) af[mf][kk] = ldA(d, mf + 4, kk);
    BARRIER();
    __builtin_amdgcn_s_setprio(1);
#pragma unroll
    for (int mf = 0; mf < 4; mf++)
#pragma unroll
      for (int nf = 0; nf < 2; nf++)
#pragma unroll
        for (int kk = 0; kk < 2; kk++)
          acc[mf + 4][nf] = __builtin_amdgcn_mfma_f32_16x16x32_bf16(af[mf][kk], bfr[nf][kk], acc[mf + 4][nf], 0, 0, 0);
    __builtin_amdgcn_s_setprio(0);
    BARRIER();

    if (kt + 2 < NKT) {
      issueHalf(kt + 2, 0);
      asm volatile("s_waitcnt vmcnt(4)" ::: "memory");
    } else if (kt + 1 < NKT) {
      asm volatile("s_waitcnt vmcnt(0)" ::: "memory");
    }
    BARRIER();
    __builtin_amdgcn_s_setprio(1);
#pragma unroll
    for (int mf = 0; mf < 4; mf++)
#pragma unroll
      for (int nf = 2; nf < 4; nf++)
#pragma unroll
        for (int kk = 0; kk < 2; kk++)
          acc[mf + 4][nf] = __builtin_amdgcn_mfma_f32_16x16x32_bf16(af[mf][kk], bfr[nf][kk], acc[mf + 4][nf], 0, 0, 0);
    __builtin_amdgcn_s_setprio(0);
    BARRIER();
  }

#pragma unroll
  for (int nf = 0; nf < 4; nf++) {
    const int gcol = bn + wc * 64 + nf * 16 + r;
    const float bv = HAS_BIAS ? bias[gcol] : 0.f;
#pragma unroll
    for (int mf = 0; mf < 8; mf++) {
#pragma unroll
      for (int j = 0; j < 4; j++) {
        const int grow = bm + wr * 128 + mf * 16 + 4 * g + j;
        float v = acc[mf][nf][j] + bv;
        if constexpr (OUT_BF16)
          ((__hip_bfloat16*)Cv)[(size_t)grow * N + gcol] = __float2bfloat16(v);
        else
          ((float*)Cv)[(size_t)grow * N + gcol] = v;
      }
    }
  }
}

// ---------------- RoPE on Q and K head slots (in-place, bf16, x4 vec) ------
__global__ __launch_bounds__(256)
void rope_qk(__hip_bfloat16* __restrict__ QKV, const float* __restrict__ cosb,
             const float* __restrict__ sinb) {
  int i = blockIdx.x * 256 + threadIdx.x;   // 2,097,152 threads
  int d = (i & 15) * 4;
  int hh = (i >> 4) & 31;
  int row = i >> 9;
  int cb = (hh < NHQ) ? hh * HD : HID + (hh - NHQ) * HD;
  unsigned short* base = (unsigned short*)QKV + (size_t)row * NQKV + cb;
  float4 c = *(const float4*)&cosb[row * HD + d];
  float4 sn = *(const float4*)&sinb[row * HD + d];
  ushort4 u1 = *(const ushort4*)(base + d);
  ushort4 u2 = *(const ushort4*)(base + d + 64);
  float x1[4] = {bf2f(u1.x), bf2f(u1.y), bf2f(u1.z), bf2f(u1.w)};
  float x2[4] = {bf2f(u2.x), bf2f(u2.y), bf2f(u2.z), bf2f(u2.w)};
  float cc[4] = {c.x, c.y, c.z, c.w};
  float ss[4] = {sn.x, sn.y, sn.z, sn.w};
  ushort4 o1, o2;
  o1.x = f2bf(x1[0] * cc[0] - x2[0] * ss[0]); o2.x = f2bf(x2[0] * cc[0] + x1[0] * ss[0]);
  o1.y = f2bf(x1[1] * cc[1] - x2[1] * ss[1]); o2.y = f2bf(x2[1] * cc[1] + x1[1] * ss[1]);
  o1.z = f2bf(x1[2] * cc[2] - x2[2] * ss[2]); o2.z = f2bf(x2[2] * cc[2] + x1[2] * ss[2]);
  o1.w = f2bf(x1[3] * cc[3] - x2[3] * ss[3]); o2.w = f2bf(x2[3] * cc[3] + x1[3] * ss[3]);
  *(ushort4*)(base + d) = o1;
  *(ushort4*)(base + d + 64) = o2;
}

// ---------------- V transpose: Vt[b][kv][d][s] = V[b][s][kv][d] ------------
__global__ __launch_bounds__(256)
void v_transpose(const __hip_bfloat16* __restrict__ QKV, __hip_bfloat16* __restrict__ Vt) {
  int i = blockIdx.x * 256 + threadIdx.x;
  int s = i & (SEQ - 1);
  int d = (i >> 11) & (HD - 1);
  int kv = (i >> 18) & 3;
  int b = i >> 20;
  Vt[i] = QKV[(size_t)(b * SEQ + s) * NQKV + HID + 512 + kv * HD + d];
}

// ---------------- Flash attention: 32x32 MFMA, streaming 32-col passes -----
// 4 waves x 32 q-rows, KVBLK=64 staged, compute in two 32-col passes.
// Swapped QK^T: s = mfma_32x32(K, Q) -> lane l holds
// S^T[kv0+(j&3)+8(j>>2)+4hf][q=qw+(l&31)], hf=l>>5. Softmax per-lane +
// one shfl_xor(32). PV B-frags built transiently via permlane32_swap.
__global__ __launch_bounds__(256, 2)
void attn_fwd(const __hip_bfloat16* __restrict__ QKV, const __hip_bfloat16* __restrict__ Vt,
              __hip_bfloat16* __restrict__ AO) {
  const int qb = 15 - blockIdx.x;           // LPT: longest blocks first
  const int head = blockIdx.y;              // 0..27
  const int b = blockIdx.z;                 // 0..1
  const int kvh = head / GRP;
  const int tid = threadIdx.x;
  const int w = tid >> 6, l = tid & 63;
  const int q32 = l & 31;                   // lane's q within wave tile
  const int hf = l >> 5;                    // lane half
  const int qw = qb * 128 + w * 32;         // wave's first q row
  const float scl2 = 0.12751744055204955f;  // (1/sqrt(128)) * log2(e)
  const float NEGINF = -__builtin_inff();

  __shared__ __align__(16) __hip_bfloat16 Ks[2][64 * 128];   // 2x16 KB, swizzled
  __shared__ __align__(16) __hip_bfloat16 Vs[2][128 * 64];   // 2x16 KB, swizzled

  const char* Kb = (const char*)(QKV + (size_t)(b * SEQ) * NQKV + HID + kvh * HD);
  const char* Vb = (const char*)(Vt + (size_t)((b * NKVH + kvh) * HD) * SEQ);
  const __hip_bfloat16* Qb = QKV + (size_t)(b * SEQ + qw) * NQKV + head * HD;

  // Q fragments (B-operand, 32x32x16): qf[c] = Q[qw+q32][16c + 8hf + 0..7]
  bf16x8 qf[8];
#pragma unroll
  for (int c = 0; c < 8; c++)
    qf[c] = *(const bf16x8*)&Qb[(size_t)q32 * NQKV + c * 16 + 8 * hf];

  f32x16 of[4] = {};
  float mrow = -3e38f, lsum = 0.f;

  const int ntiles = 2 * qb + 2;

  auto stage = [&](int buf, int kv0) {
#pragma unroll
    for (int p = 0; p < 4; p++) {
      const int row = w * 16 + p * 4 + (l >> 4);      // K tile row (local)
      const int cb = (l & 15) * 16;
      gload_lds16(Kb + (size_t)(kv0 + row) * (NQKV * 2) + (cb ^ ((row & 7) << 4)),
                  (char*)(Ks[buf]) + w * 4096 + p * 1024);
    }
#pragma unroll
    for (int p = 0; p < 4; p++) {
      const int row = w * 32 + p * 8 + (l >> 3);      // V^T tile row (= d)
      const int cb = (l & 7) * 16;
      gload_lds16(Vb + (size_t)row * (SEQ * 2) + (size_t)kv0 * 2 + (cb ^ ((row & 7) << 4)),
                  (char*)(Vs[buf]) + w * 4096 + p * 1024);
    }
  };

  stage(0, 0);
  __syncthreads();

  const int swz = (q32 & 7) << 4;   // row&7 == q32&7 for all our LDS reads
  const int qg = qw + q32;

  for (int t = 0; t < ntiles; t++) {
    const int cur = t & 1;
    if (t + 1 < ntiles) stage(cur ^ 1, t * 64 + 64);  // prefetch under compute

#pragma unroll
    for (int half = 0; half < 2; half++) {
      const int kv0 = t * 64 + half * 32;
      if (kv0 <= qw + 31) {
        // ---- QK^T swapped, 32x32x16 (one 32-col pass)
        f32x16 s = {};
        const char* kb = (const char*)(Ks[cur]) + (half * 32 + q32) * 256;
#pragma unroll
        for (int c = 0; c < 8; c++) {
          bf16x8 kf = *(const bf16x8*)(kb + ((c * 32 + 16 * hf) ^ swz));
          s = __builtin_amdgcn_mfma_f32_32x32x16_bf16(kf, qf[c], s, 0, 0, 0);
        }

        // ---- mask + scale + per-lane max
        float pmax = -3e38f;
        if (kv0 + 31 <= qw) {               // interior pass: no mask
#pragma unroll
          for (int j = 0; j < 16; j++) { s[j] *= scl2; pmax = fmaxf(pmax, s[j]); }
        } else {
#pragma unroll
          for (int j = 0; j < 16; j++) {
            const int kvl = (j & 3) + 8 * (j >> 2) + 4 * hf;
            s[j] = (kv0 + kvl <= qg) ? s[j] * scl2 : NEGINF;
            pmax = fmaxf(pmax, s[j]);
          }
        }
        pmax = fmaxf(pmax, __shfl_xor(pmax, 32));

        // ---- online softmax, defer-max (THR=11.5 in log2 domain)
        float rs = 0.f;
        if (__all(pmax - mrow <= 11.5f)) {
#pragma unroll
          for (int j = 0; j < 16; j++) { float p = exp2f(s[j] - mrow); s[j] = p; rs += p; }
        } else {
          const float nm = fmaxf(mrow, pmax);
          const float al = exp2f(mrow - nm);
          mrow = nm;
#pragma unroll
          for (int j = 0; j < 16; j++) { float p = exp2f(s[j] - nm); s[j] = p; rs += p; }
          lsum *= al;
#pragma unroll
          for (int db = 0; db < 4; db++) of[db] *= al;
        }
        rs += __shfl_xor(rs, 32);
        lsum += rs;

        // ---- pack P pairs -> u32 words (8 live)
        int wv[8];
#pragma unroll
        for (int k = 0; k < 8; k++)
          wv[k] = (int)((unsigned)f2bf(s[2 * k]) | ((unsigned)f2bf(s[2 * k + 1]) << 16));

        // ---- PV t4=0: pB built transiently; kv local 0..15
        {
          auto ra = __builtin_amdgcn_permlane32_swap(wv[0], wv[2], false, false);
          auto rb = __builtin_amdgcn_permlane32_swap(wv[1], wv[3], false, false);
          union { int4v i; bf16x8 h; } u;
          u.i = (int4v){(int)ra[0], (int)rb[0], (int)ra[1], (int)rb[1]};
          const bf16x8 pB = u.h;
#pragma unroll
          for (int db = 0; db < 4; db++) {
            const char* vp = (const char*)(Vs[cur]) + (db * 32 + q32) * 128;
            bf16x8 vf = *(const bf16x8*)(vp + ((half * 64 + 0 + 16 * hf) ^ swz));
            of[db] = __builtin_amdgcn_mfma_f32_32x32x16_bf16(vf, pB, of[db], 0, 0, 0);
          }
        }
        // ---- PV t4=1: kv local 16..31
        {
          auto rc = __builtin_amdgcn_permlane32_swap(wv[4], wv[6], false, false);
          auto rd = __builtin_amdgcn_permlane32_swap(wv[5], wv[7], false, false);
          union { int4v i; bf16x8 h; } u2;
          u2.i = (int4v){(int)rc[0], (int)rd[0], (int)rc[1], (int)rd[1]};
          const bf16x8 pB = u2.h;
#pragma unroll
          for (int db = 0; db < 4; db++) {
            const char* vp = (const char*)(Vs[cur]) + (db * 32 + q32) * 128;
            bf16x8 vf = *(const bf16x8*)(vp + ((half * 64 + 32 + 16 * hf) ^ swz));
            of[db] = __builtin_amdgcn_mfma_f32_32x32x16_bf16(vf, pB, of[db], 0, 0, 0);
          }
        }
      }
    }
    __syncthreads();   // drains prefetch + guards buffer reuse
  }

  // ---- epilogue: of[db] reg j -> d = 32db + 8(j>>2) + 4hf + (j&3), q = qw+q32
  unsigned short* AOu = (unsigned short*)AO;
  const float inv = 1.0f / lsum;
  const size_t rowb = (size_t)(b * SEQ + qw + q32) * HID + head * HD;
#pragma unroll
  for (int db = 0; db < 4; db++) {
#pragma unroll
    for (int qd = 0; qd < 4; qd++) {
      ushort4 o;
      o.x = f2bf(of[db][4 * qd + 0] * inv);
      o.y = f2bf(of[db][4 * qd + 1] * inv);
      o.z = f2bf(of[db][4 * qd + 2] * inv);
      o.w = f2bf(of[db][4 * qd + 3] * inv);
      *(ushort4*)&AOu[rowb + db * 32 + 8 * qd + 4 * hf] = o;
    }
  }
}

// ---------------------------------------------------------------------------
extern "C" void kernel_launch(void* const* d_in, const int* in_sizes, int n_in,
                              void* d_out, int out_size, void* d_ws, size_t ws_size,
                              hipStream_t stream) {
  const float* hs = (const float*)d_in[0];
  const float* cosb = (const float*)d_in[1];
  const float* sinb = (const float*)d_in[2];
  const float* Wq = (const float*)d_in[3];
  const float* bq = (const float*)d_in[4];
  const float* Wk = (const float*)d_in[5];
  const float* bk = (const float*)d_in[6];
  const float* Wv = (const float*)d_in[7];
  const float* bv = (const float*)d_in[8];
  const float* Wo = (const float*)d_in[9];

  char* ws = (char*)d_ws;
  __hip_bfloat16* Xb = (__hip_bfloat16*)(ws);
  __hip_bfloat16* Wcat = (__hip_bfloat16*)(ws + 29360128);
  float* bcat = (float*)(ws + 62390272);
  __hip_bfloat16* QKVb = (__hip_bfloat16*)(ws + 62408704);
  __hip_bfloat16* Vt = (__hip_bfloat16*)(ws + 100157440);
  __hip_bfloat16* AOb = Xb;    // X dead after QKV GEMM
  __hip_bfloat16* Wob = Wcat;  // Wcat dead after QKV GEMM

  // Conversions to bf16
  cvt_f32_bf16<<<14336, 256, 0, stream>>>(hs, Xb, 3670016);                       // X
  cvt_f32_bf16<<<12544, 256, 0, stream>>>(Wq, Wcat, 3211264);                     // Wq rows 0..3583
  cvt_f32_bf16<<<1792, 256, 0, stream>>>(Wk, Wcat + (size_t)3584 * 3584, 458752); // Wk rows 3584..4095
  cvt_f32_bf16<<<1792, 256, 0, stream>>>(Wv, Wcat + (size_t)4096 * 3584, 458752); // Wv rows 4096..4607
  concat_bias<<<18, 256, 0, stream>>>(bq, bk, bv, bcat);

  // Fused QKV projection: [4096 x 3584] @ [4608 x 3584]^T + bias -> bf16
  gemm256<true, true><<<288, 512, 0, stream>>>(Xb, Wcat, bcat, QKVb, 4096, NQKV, HID, 16);

  // RoPE on Q + K head slots (in place, vectorized x4)
  rope_qk<<<8192, 256, 0, stream>>>(QKVb, cosb, sinb);

  // V transpose for PV fragment loads
  v_transpose<<<8192, 256, 0, stream>>>(QKVb, Vt);

  // Wo conversion (into the now-dead Wcat region)
  cvt_f32_bf16<<<12544, 256, 0, stream>>>(Wo, Wob, 3211264);

  // Flash attention: 128-row Q blocks, 4 waves x 32 rows, 64-col KV tiles
  dim3 ga(16, NHQ, 2);
  attn_fwd<<<ga, 256, 0, stream>>>(QKVb, Vt, AOb);

  // O projection -> f32 out
  gemm256<false, false><<<224, 512, 0, stream>>>(AOb, Wob, nullptr, d_out, 4096, HID, HID, 16);
}